// Round 3
// baseline (785.778 us; speedup 1.0000x reference)
//
#include <hip/hip_runtime.h>
#include <stdint.h>

// Shapes are fixed by the reference: B=2, S=2048, D=1024, H=16, hd=64.
#define SLEN 2048
#define NHEAD 16

typedef __attribute__((ext_vector_type(8))) short vbf8;   // 8 x bf16 (4 VGPRs)
typedef __attribute__((ext_vector_type(4))) float vf4;    // MFMA accumulator

#define MFMA16(a, b, c) __builtin_amdgcn_mfma_f32_16x16x32_bf16((a), (b), (c), 0, 0, 0)

__device__ __forceinline__ short f2bf(float f) {
  union { float f; uint32_t u; } x; x.f = f;
  uint32_t r = x.u + 0x7fffu + ((x.u >> 16) & 1u);  // RNE
  return (short)(r >> 16);
}
__device__ __forceinline__ float bf2f(short s) {
  union { float f; uint32_t u; } x; x.u = ((uint32_t)(uint16_t)s) << 16;
  return x.f;
}

__device__ __forceinline__ void gld16(const void* g, void* l) {
  __builtin_amdgcn_global_load_lds(
      (const __attribute__((address_space(1))) uint32_t*)g,
      (__attribute__((address_space(3))) uint32_t*)l, 16, 0, 0);
}

// ---------------- fp32 -> bf16 convert (n8 = elements/8) ----------------
__global__ __launch_bounds__(256) void cvt_kernel(const float* __restrict__ src,
                                                  short* __restrict__ dst, int n8) {
  int i = blockIdx.x * 256 + threadIdx.x;
  if (i >= n8) return;
  const float4* s4 = (const float4*)src;
  float4 a = s4[2 * i], b = s4[2 * i + 1];
  vbf8 o;
  o[0] = f2bf(a.x); o[1] = f2bf(a.y); o[2] = f2bf(a.z); o[3] = f2bf(a.w);
  o[4] = f2bf(b.x); o[5] = f2bf(b.y); o[6] = f2bf(b.z); o[7] = f2bf(b.w);
  *(vbf8*)&dst[8 * i] = o;
}

// ---------------- 128x128 GEMM-BT (m97 structure), K=1024 ----------------
// A [M][1024] bf16 row-major, B [N][1024] bf16 row-major (weights: y = x @ W^T).
// MODE 0: qkv projection, grid.z selects W/bias/scale/dst; writes bf16 [B,H,S,hd].
// MODE 1: out projection; writes fp32 [B,S,D] to d_out.
template <int MODE>
__global__ __launch_bounds__(256, 2)
void gemm128(const short* __restrict__ A, const short* __restrict__ B0,
             const short* __restrict__ B1, const short* __restrict__ B2,
             const float* __restrict__ bias0, const float* __restrict__ bias2,
             float scale,
             short* __restrict__ dq, short* __restrict__ dk, short* __restrict__ dv,
             const float* __restrict__ biasO, float* __restrict__ outF) {
  __shared__ __align__(16) short Ash[128 * 32];
  __shared__ __align__(16) short Bsh[128 * 32];
  const int tid = threadIdx.x, lane = tid & 63, w = tid >> 6;
  const int r16 = lane & 15, g = lane >> 4;
  const int wr = w >> 1, wc = w & 1;
  const int m0 = blockIdx.y * 128, n0 = blockIdx.x * 128;

  const short* Bsel;
  const float* bias;
  float sc;
  if (MODE == 0) {
    int z = blockIdx.z;
    Bsel = (z == 0) ? B0 : ((z == 1) ? B1 : B2);
    bias = (z == 0) ? bias0 : ((z == 1) ? (const float*)nullptr : bias2);
    sc = (z == 2) ? 1.0f : scale;
  } else {
    Bsel = B0; bias = biasO; sc = 1.0f;
  }

  vf4 acc[4][4] = {};

  const int srow = (w << 4) + (lane >> 2);   // + p*64
  const int scol = (lane & 3) << 3;
  const short* aS = A + (size_t)(m0 + srow) * 1024 + scol;
  const short* bS = Bsel + (size_t)(n0 + srow) * 1024 + scol;
  short* aLb = &Ash[w << 9];  // wave-uniform LDS base (HW adds lane*16B)
  short* bLb = &Bsh[w << 9];

  for (int kt = 0; kt < 32; ++kt) {
    const int k0 = kt << 5;
    __syncthreads();
    gld16(aS + k0, aLb);
    gld16(aS + 65536 + k0, aLb + 2048);
    gld16(bS + k0, bLb);
    gld16(bS + 65536 + k0, bLb + 2048);
    asm volatile("s_waitcnt vmcnt(0)" ::: "memory");
    __syncthreads();

    vbf8 af[4], bf[4];
#pragma unroll
    for (int mi = 0; mi < 4; mi++)
      af[mi] = *(const vbf8*)&Ash[(wr * 64 + mi * 16 + r16) * 32 + (g << 3)];
#pragma unroll
    for (int ni = 0; ni < 4; ni++)
      bf[ni] = *(const vbf8*)&Bsh[(wc * 64 + ni * 16 + r16) * 32 + (g << 3)];
#pragma unroll
    for (int mi = 0; mi < 4; mi++)
#pragma unroll
      for (int ni = 0; ni < 4; ni++)
        acc[mi][ni] = MFMA16(af[mi], bf[ni], acc[mi][ni]);
  }

  // epilogue: D layout col = lane&15, row = (lane>>4)*4 + j
  short* dst = nullptr;
  if (MODE == 0) dst = (blockIdx.z == 0) ? dq : ((blockIdx.z == 1) ? dk : dv);
#pragma unroll
  for (int ni = 0; ni < 4; ni++) {
    const int col = n0 + wc * 64 + ni * 16 + r16;
    const float bb = bias ? bias[col] : 0.0f;
    const int h = col >> 6, d = col & 63;
#pragma unroll
    for (int mi = 0; mi < 4; mi++) {
#pragma unroll
      for (int j = 0; j < 4; j++) {
        const int row = m0 + wr * 64 + mi * 16 + (g << 2) + j;  // global token
        const float v = (acc[mi][ni][j] + bb) * sc;
        if (MODE == 0) {
          const int bb_ = row >> 11, s = row & 2047;
          dst[((size_t)((bb_ << 4) + h) * SLEN + s) * 64 + d] = f2bf(v);
        } else {
          outF[(size_t)row * 1024 + col] = v;
        }
      }
    }
  }
}

// ---------------- RoPE in-place on bf16 Q/K, [B,H,S,64] ----------------
__global__ __launch_bounds__(256)
void rope_kernel(const int* __restrict__ pos_ids, short* __restrict__ qh,
                 short* __restrict__ kh) {
  const int t = (blockIdx.x << 2) + (threadIdx.x >> 6);  // token 0..4095
  const int lane = threadIdx.x & 63;
  const int pos = pos_ids[t];
  const int dh = lane & 31;
  // inv_freq = 10000^(-2*dh/64) ; log2(10000) = 13.287712379549449
  const float f = (float)pos * exp2f((float)dh * (-2.0f / 64.0f) * 13.287712379549449f);
  float sn, cs;
  sincosf(f, &sn, &cs);
  const int b = t >> 11, s = t & 2047;
  const float sgn = (lane < 32) ? -1.0f : 1.0f;
#pragma unroll
  for (int h = 0; h < NHEAD; ++h) {
    const size_t base = ((size_t)(((b << 4) + h) * SLEN + s)) << 6;
    {
      float v = bf2f(qh[base + lane]);
      float p = bf2f(qh[base + (lane ^ 32)]);
      qh[base + lane] = f2bf(v * cs + sgn * p * sn);
    }
    {
      float v = bf2f(kh[base + lane]);
      float p = bf2f(kh[base + (lane ^ 32)]);
      kh[base + lane] = f2bf(v * cs + sgn * p * sn);
    }
  }
}

// ---------------- fused attention: qk out + online softmax + PV ----------------
// grid (S/128, B*H); block 256 (4 waves, 32 q-rows each); k-tiles of 128.
__device__ __forceinline__ int vprm(int d) {  // row permutation for Vt bank spread
  return (d & 56) | ((d + (d >> 3)) & 7);
}

__global__ __launch_bounds__(256, 2)
void attn_kernel(const short* __restrict__ qh, const short* __restrict__ kh,
                 const short* __restrict__ vh, const int* __restrict__ mask,
                 float* __restrict__ qkout, short* __restrict__ ob) {
  __shared__ __align__(16) short Ksh[128 * 72];   // [k-pos][d], stride 72
  __shared__ __align__(16) short Vts[64 * 136];   // [perm(d)][k-pos], stride 136
  __shared__ __align__(16) short Psh[128 * 136];  // [q-row][k-pos], stride 136

  const int tid = threadIdx.x, lane = tid & 63, w = tid >> 6;
  const int r16 = lane & 15, g = lane >> 4;
  const int bh = blockIdx.y, b = bh >> 4, h = bh & 15;
  const int q0 = blockIdx.x * 128;
  const size_t headoff = (size_t)bh * SLEN * 64;
  const short* Qb = qh + headoff;
  const short* Kb = kh + headoff;
  const short* Vb = vh + headoff;

  // Q fragments held in registers: rows w*32 + mi*16 + r16, k = kk*32 + g*8
  vbf8 qf[2][2];
#pragma unroll
  for (int mi = 0; mi < 2; mi++)
#pragma unroll
    for (int kk = 0; kk < 2; kk++)
      qf[mi][kk] = *(const vbf8*)&Qb[(size_t)(q0 + w * 32 + mi * 16 + r16) * 64 + kk * 32 + g * 8];

  float mrun[2][4], lrun[2][4];
  vf4 oacc[2][4] = {};
#pragma unroll
  for (int mi = 0; mi < 2; mi++)
#pragma unroll
    for (int j = 0; j < 4; j++) { mrun[mi][j] = -__builtin_inff(); lrun[mi][j] = 0.0f; }

  for (int kt = 0; kt < SLEN / 128; ++kt) {
    const int kbase = kt * 128;
    // per-lane mask bits for this tile's 8 column groups
    unsigned mbits = 0;
#pragma unroll
    for (int ni = 0; ni < 8; ni++)
      if (mask[b * SLEN + kbase + ni * 16 + r16] == 0) mbits |= 1u << ni;

    __syncthreads();  // previous tile fully consumed
    // stage K -> LDS [128][72]
#pragma unroll
    for (int p = 0; p < 4; p++) {
      const int c = p * 256 + tid;           // 1024 chunks of 8 shorts
      const int sr = c >> 3, d0 = (c & 7) * 8;
      vbf8 kv = *(const vbf8*)&Kb[(size_t)(kbase + sr) * 64 + d0];
      *(vbf8*)&Ksh[sr * 72 + d0] = kv;
    }
    // stage V^T -> LDS (row-permuted)
#pragma unroll
    for (int p = 0; p < 4; p++) {
      const int c = p * 256 + tid;
      const int sr = c >> 3, d0 = (c & 7) * 8;
      vbf8 vv = *(const vbf8*)&Vb[(size_t)(kbase + sr) * 64 + d0];
#pragma unroll
      for (int j = 0; j < 8; j++) Vts[vprm(d0 + j) * 136 + sr] = vv[j];
    }
    __syncthreads();

    // ---- S = Q K^T  (fp32 accum) ----
    vf4 sacc[2][8] = {};
#pragma unroll
    for (int ni = 0; ni < 8; ni++) {
      vbf8 kf0 = *(const vbf8*)&Ksh[(ni * 16 + r16) * 72 + g * 8];
      vbf8 kf1 = *(const vbf8*)&Ksh[(ni * 16 + r16) * 72 + 32 + g * 8];
#pragma unroll
      for (int mi = 0; mi < 2; mi++) {
        sacc[mi][ni] = MFMA16(qf[mi][0], kf0, sacc[mi][ni]);
        sacc[mi][ni] = MFMA16(qf[mi][1], kf1, sacc[mi][ni]);
      }
    }

    // ---- mask + write qk (pre-softmax, fp32) ----
#pragma unroll
    for (int mi = 0; mi < 2; mi++) {
      const size_t rowbase = ((size_t)bh * SLEN + (q0 + w * 32 + mi * 16 + g * 4)) * SLEN;
#pragma unroll
      for (int ni = 0; ni < 8; ni++) {
        if ((mbits >> ni) & 1) {
          sacc[mi][ni][0] = -__builtin_inff(); sacc[mi][ni][1] = -__builtin_inff();
          sacc[mi][ni][2] = -__builtin_inff(); sacc[mi][ni][3] = -__builtin_inff();
        }
        const int col = kbase + ni * 16 + r16;
#pragma unroll
        for (int j = 0; j < 4; j++) qkout[rowbase + (size_t)j * SLEN + col] = sacc[mi][ni][j];
      }
    }

    // ---- online softmax (rows replicated across 16-lane col groups) ----
#pragma unroll
    for (int mi = 0; mi < 2; mi++) {
#pragma unroll
      for (int j = 0; j < 4; j++) {
        float mx = sacc[mi][0][j];
#pragma unroll
        for (int ni = 1; ni < 8; ni++) mx = fmaxf(mx, sacc[mi][ni][j]);
        mx = fmaxf(mx, __shfl_xor(mx, 1));
        mx = fmaxf(mx, __shfl_xor(mx, 2));
        mx = fmaxf(mx, __shfl_xor(mx, 4));
        mx = fmaxf(mx, __shfl_xor(mx, 8));
        const float mnew = fmaxf(mrun[mi][j], mx);
        const float corr = (mnew <= -3e38f) ? 0.0f : __expf(mrun[mi][j] - mnew);
        float rs = 0.0f;
#pragma unroll
        for (int ni = 0; ni < 8; ni++) {
          const float sval = sacc[mi][ni][j];
          const float p = (sval <= -3e38f) ? 0.0f : __expf(sval - mnew);
          rs += p;
          sacc[mi][ni][j] = p;
        }
        rs += __shfl_xor(rs, 1);
        rs += __shfl_xor(rs, 2);
        rs += __shfl_xor(rs, 4);
        rs += __shfl_xor(rs, 8);
        lrun[mi][j] = lrun[mi][j] * corr + rs;
        mrun[mi][j] = mnew;
#pragma unroll
        for (int nd = 0; nd < 4; nd++) oacc[mi][nd][j] *= corr;
      }
    }

    // ---- P -> LDS (bf16, wave-private rows) ----
#pragma unroll
    for (int mi = 0; mi < 2; mi++) {
      const int rb = w * 32 + mi * 16 + g * 4;
#pragma unroll
      for (int ni = 0; ni < 8; ni++) {
        const int colp = ni * 16 + r16;
#pragma unroll
        for (int j = 0; j < 4; j++) Psh[(rb + j) * 136 + colp] = f2bf(sacc[mi][ni][j]);
      }
    }

    // ---- O += P V  (same-wave LDS RAW; compiler inserts lgkmcnt) ----
#pragma unroll
    for (int ks = 0; ks < 4; ks++) {
      vbf8 vb[4];
#pragma unroll
      for (int nd = 0; nd < 4; nd++)
        vb[nd] = *(const vbf8*)&Vts[vprm(nd * 16 + r16) * 136 + ks * 32 + g * 8];
#pragma unroll
      for (int mi = 0; mi < 2; mi++) {
        vbf8 pa = *(const vbf8*)&Psh[(w * 32 + mi * 16 + r16) * 136 + ks * 32 + g * 8];
#pragma unroll
        for (int nd = 0; nd < 4; nd++) oacc[mi][nd] = MFMA16(pa, vb[nd], oacc[mi][nd]);
      }
    }
  }

  // ---- epilogue: O /= l, write bf16 [B,S,H*hd] ----
#pragma unroll
  for (int mi = 0; mi < 2; mi++) {
#pragma unroll
    for (int j = 0; j < 4; j++) {
      const float linv = (lrun[mi][j] > 0.0f) ? 1.0f / lrun[mi][j] : 0.0f;
      const int row = q0 + w * 32 + mi * 16 + g * 4 + j;  // s index
      const size_t obase = ((size_t)(b * SLEN + row)) * 1024 + h * 64;
#pragma unroll
      for (int nd = 0; nd < 4; nd++)
        ob[obase + nd * 16 + r16] = f2bf(oacc[mi][nd][j] * linv);
    }
  }
}

// ---------------- host-side launcher ----------------
extern "C" void kernel_launch(void* const* d_in, const int* in_sizes, int n_in,
                              void* d_out, int out_size, void* d_ws, size_t ws_size,
                              hipStream_t stream) {
  const float* x  = (const float*)d_in[0];
  const int* msk  = (const int*)d_in[1];
  const int* pos  = (const int*)d_in[2];
  // d_in[3] = n_head (16, hardcoded)
  const float* Wq = (const float*)d_in[4];
  const float* bq = (const float*)d_in[5];
  const float* Wk = (const float*)d_in[6];
  const float* Wv = (const float*)d_in[7];
  const float* bv = (const float*)d_in[8];
  const float* Wo = (const float*)d_in[9];
  const float* bo = (const float*)d_in[10];

  float* outp = (float*)d_out;                 // [2,2048,1024] fp32
  float* qkout = outp + (size_t)4194304;       // [2,16,2048,2048] fp32

  // workspace layout (needs 48 MiB)
  char* ws = (char*)d_ws;
  short* xb  = (short*)(ws + 0);          // x bf16            8 MiB
  short* wqb = (short*)(ws + 8388608);    // Wq bf16           2 MiB
  short* wkb = (short*)(ws + 10485760);
  short* wvb = (short*)(ws + 12582912);
  short* wob = (short*)(ws + 14680064);
  short* qh  = (short*)(ws + 16777216);   // Q [B,H,S,64] bf16 8 MiB
  short* kh  = (short*)(ws + 25165824);
  short* vh  = (short*)(ws + 33554432);
  short* ob  = (short*)(ws + 41943040);   // O [B,S,1024] bf16 8 MiB

  cvt_kernel<<<2048, 256, 0, stream>>>(x, xb, 524288);
  cvt_kernel<<<512, 256, 0, stream>>>(Wq, wqb, 131072);
  cvt_kernel<<<512, 256, 0, stream>>>(Wk, wkb, 131072);
  cvt_kernel<<<512, 256, 0, stream>>>(Wv, wvb, 131072);
  cvt_kernel<<<512, 256, 0, stream>>>(Wo, wob, 131072);

  // scale = hd^(-0.25) = 64^(-0.25)
  gemm128<0><<<dim3(8, 32, 3), 256, 0, stream>>>(xb, wqb, wkb, wvb, bq, bv,
                                                 0.35355339059327373f,
                                                 qh, kh, vh, nullptr, nullptr);
  rope_kernel<<<1024, 256, 0, stream>>>(pos, qh, kh);
  attn_kernel<<<dim3(16, 32), 256, 0, stream>>>(qh, kh, vh, msk, qkout, ob);
  gemm128<1><<<dim3(8, 32), 256, 0, stream>>>(ob, wob, nullptr, nullptr, nullptr, nullptr,
                                              1.0f, nullptr, nullptr, nullptr, bo, outp);
}